// Round 1
// baseline (466.982 us; speedup 1.0000x reference)
//
#include <hip/hip_runtime.h>
#include <hip/hip_bf16.h>
#include <cstddef>

// Problem constants (from reference)
#define QN 10000
#define DD 64
#define MM 50
#define BB 64
#define TT 512

// ---------------------------------------------------------------------------
// Kernel 1: per-(b,t) precompute of w (softmax(k@Mk^T)), e (sigmoid), a (tanh)
// One wave per row; Mk row / e_W col / a_W col held in VGPRs (192 regs),
// k/v rows are wave-uniform -> scalar loads.
// ---------------------------------------------------------------------------
__global__ __launch_bounds__(256) void k1_pre(
    const int* __restrict__ question, const int* __restrict__ response,
    const float* __restrict__ k_emb, const float* __restrict__ v_emb,
    const float* __restrict__ Mk,
    const float* __restrict__ e_W, const float* __restrict__ e_b,
    const float* __restrict__ a_W, const float* __restrict__ a_b,
    float* __restrict__ w_buf, float* __restrict__ e_buf, float* __restrict__ a_buf) {
  const int lane = threadIdx.x & 63;
  const int wslot = __builtin_amdgcn_readfirstlane((int)(threadIdx.x >> 6));
  const int wid = blockIdx.x * 4 + wslot;

  // Per-lane weight fragments in registers.
  float mk[64], ew[64], aw[64];
  const int mrow = lane < MM ? lane : (MM - 1);
#pragma unroll
  for (int i = 0; i < 64; i += 4) {
    const float4 t4 = *(const float4*)(Mk + mrow * 64 + i);
    mk[i] = t4.x; mk[i + 1] = t4.y; mk[i + 2] = t4.z; mk[i + 3] = t4.w;
  }
#pragma unroll
  for (int i = 0; i < 64; ++i) {
    ew[i] = e_W[i * 64 + lane];   // column lane of e_W (coalesced, cached)
    aw[i] = a_W[i * 64 + lane];
  }
  const float eb = e_b[lane];
  const float ab = a_b[lane];

  for (int row = wid; row < BB * TT; row += 2048) {
    const int q = question[row];           // wave-uniform
    const int r = response[row];
    const float* __restrict__ krow = k_emb + (size_t)q * 64;
    const float* __restrict__ vrow = v_emb + ((size_t)q + (size_t)QN * r) * 64;

    // logits: lane m computes k . Mk[m]
    float lm = 0.f;
#pragma unroll
    for (int i = 0; i < 64; ++i) lm = fmaf(krow[i], mk[i], lm);

    // softmax over lanes 0..49
    float lv = (lane < MM) ? lm : -3.4e38f;
#pragma unroll
    for (int off = 32; off > 0; off >>= 1) lv = fmaxf(lv, __shfl_xor(lv, off));
    float pe = (lane < MM) ? __expf(lm - lv) : 0.f;
    float ss = pe;
#pragma unroll
    for (int off = 32; off > 0; off >>= 1) ss += __shfl_xor(ss, off);
    const float wval = pe / ss;
    if (lane < MM) w_buf[(size_t)row * MM + lane] = wval;

    // e = sigmoid(v @ e_W + e_b), a = tanh(v @ a_W + a_b); lane d = output col
    float se = eb, sa = ab;
#pragma unroll
    for (int i = 0; i < 64; ++i) {
      const float vi = vrow[i];
      se = fmaf(vi, ew[i], se);
      sa = fmaf(vi, aw[i], sa);
    }
    const float ev = 1.f / (1.f + __expf(-se));
    const float t2 = __expf(2.f * sa);
    const float av = 1.f - 2.f / (t2 + 1.f);   // tanh, saturates correctly
    e_buf[(size_t)row * 64 + lane] = ev;
    a_buf[(size_t)row * 64 + lane] = av;
  }
}

// ---------------------------------------------------------------------------
// Kernel 2: sequential memory scan. One block per batch, 4 waves;
// wave g owns m in [16g, 16g+16), lane = d. State s[16] in registers.
// w_t wave-uniform (scalar loads); cross-wave read-reduction via LDS.
// ---------------------------------------------------------------------------
__global__ __launch_bounds__(256) void k2_scan(
    const float* __restrict__ w_buf, const float* __restrict__ e_buf,
    const float* __restrict__ a_buf, const float* __restrict__ mask,
    const float* __restrict__ Mv0, float* __restrict__ read_buf) {
  const int b = blockIdx.x;
  const int tid = (int)threadIdx.x;
  const int lane = tid & 63;            // d index
  const int g = tid >> 6;               // m-group
  const int gu = __builtin_amdgcn_readfirstlane(g);

  __shared__ float ps[2][4][64];

  // init state from Mv0 (broadcast over batch)
  float s[16];
#pragma unroll
  for (int j = 0; j < 16; ++j) {
    const int m = gu * 16 + j;
    const int mc = m < MM ? m : (MM - 1);
    const float v = Mv0[mc * 64 + lane];
    s[j] = (m < MM) ? v : 0.f;
  }

  // prefetch t = 0
  float wv[16], ed, ad, mv;
  {
    const float* __restrict__ wr = w_buf + (size_t)(b * TT) * MM;
#pragma unroll
    for (int j = 0; j < 16; ++j) {
      const int m = gu * 16 + j;
      const int mc = m < MM ? m : (MM - 1);
      const float x = wr[mc];
      wv[j] = (m < MM) ? x : 0.f;
    }
    ed = e_buf[(size_t)(b * TT) * 64 + lane];
    ad = a_buf[(size_t)(b * TT) * 64 + lane];
    mv = mask[b * TT];
  }

  for (int t = 0; t < TT; ++t) {
    // prefetch t+1 (issued before this iteration's barrier -> latency hidden)
    float wvn[16], edn, adn, mvn;
    if (t + 1 < TT) {
      const float* __restrict__ wr = w_buf + (size_t)(b * TT + t + 1) * MM;
#pragma unroll
      for (int j = 0; j < 16; ++j) {
        const int m = gu * 16 + j;
        const int mc = m < MM ? m : (MM - 1);
        const float x = wr[mc];
        wvn[j] = (m < MM) ? x : 0.f;
      }
      edn = e_buf[(size_t)(b * TT + t + 1) * 64 + lane];
      adn = a_buf[(size_t)(b * TT + t + 1) * 64 + lane];
      mvn = mask[b * TT + t + 1];
    } else {
      edn = adn = mvn = 0.f;
#pragma unroll
      for (int j = 0; j < 16; ++j) wvn[j] = 0.f;
    }

    // read at output index t-1 uses w_t and pre-update state
    if (t >= 1) {
      float acc = 0.f;
#pragma unroll
      for (int j = 0; j < 16; ++j) acc = fmaf(wv[j], s[j], acc);
      ps[t & 1][g][lane] = acc;
    }

    // state update: s = s + w*(a - s*e)   (skipped where mask != 1)
    if (mv == 1.0f) {
#pragma unroll
      for (int j = 0; j < 16; ++j) s[j] = fmaf(wv[j], fmaf(-s[j], ed, ad), s[j]);
    }

    if (t >= 1) {
      __syncthreads();
      if (g == 0) {
        const float r = ps[t & 1][0][lane] + ps[t & 1][1][lane] +
                        ps[t & 1][2][lane] + ps[t & 1][3][lane];
        read_buf[((size_t)b * (TT - 1) + (t - 1)) * 64 + lane] = r;
      }
    }

#pragma unroll
    for (int j = 0; j < 16; ++j) wv[j] = wvn[j];
    ed = edn; ad = adn; mv = mvn;
  }
}

// ---------------------------------------------------------------------------
// Kernel 3: f = tanh([read | k_{t+1}] @ f_W + f_b); p = f @ p_W + p_b
// One wave per output row; f_W columns held in VGPRs (128 regs).
// ---------------------------------------------------------------------------
__global__ __launch_bounds__(256) void k3_out(
    const int* __restrict__ question, const float* __restrict__ k_emb,
    const float* __restrict__ read_buf,
    const float* __restrict__ f_W, const float* __restrict__ f_b,
    const float* __restrict__ p_W, const float* __restrict__ p_b,
    float* __restrict__ out) {
  const int lane = threadIdx.x & 63;
  const int wslot = __builtin_amdgcn_readfirstlane((int)(threadIdx.x >> 6));
  const int wid = blockIdx.x * 4 + wslot;

  float fw[128];
#pragma unroll
  for (int i = 0; i < 128; ++i) fw[i] = f_W[i * 64 + lane];
  const float fb = f_b[lane];
  const float pw = p_W[lane];
  const float pb = p_b[0];

  for (int row = wid; row < BB * (TT - 1); row += 2048) {
    const int b = row / (TT - 1);
    const int tp = row - b * (TT - 1);
    const float* __restrict__ rrow = read_buf + (size_t)row * 64;
    const int qn = question[b * TT + tp + 1];     // wave-uniform
    const float* __restrict__ krow = k_emb + (size_t)qn * 64;

    float f = fb;
#pragma unroll
    for (int i = 0; i < 64; ++i) f = fmaf(rrow[i], fw[i], f);
#pragma unroll
    for (int i = 0; i < 64; ++i) f = fmaf(krow[i], fw[64 + i], f);

    const float t2 = __expf(2.f * f);
    const float fv = 1.f - 2.f / (t2 + 1.f);      // tanh

    float acc = fv * pw;
#pragma unroll
    for (int off = 32; off > 0; off >>= 1) acc += __shfl_xor(acc, off);
    if (lane == 0) out[row] = acc + pb;
  }
}

// ---------------------------------------------------------------------------
extern "C" void kernel_launch(void* const* d_in, const int* in_sizes, int n_in,
                              void* d_out, int out_size, void* d_ws, size_t ws_size,
                              hipStream_t stream) {
  const int*   question = (const int*)d_in[0];
  const int*   response = (const int*)d_in[1];
  const float* mask     = (const float*)d_in[2];
  const float* k_emb    = (const float*)d_in[3];
  const float* v_emb    = (const float*)d_in[4];
  const float* Mk       = (const float*)d_in[5];
  const float* Mv0      = (const float*)d_in[6];
  const float* e_W      = (const float*)d_in[7];
  const float* e_b      = (const float*)d_in[8];
  const float* a_W      = (const float*)d_in[9];
  const float* a_b      = (const float*)d_in[10];
  const float* f_W      = (const float*)d_in[11];
  const float* f_b      = (const float*)d_in[12];
  const float* p_W      = (const float*)d_in[13];
  const float* p_b      = (const float*)d_in[14];
  float* out = (float*)d_out;

  float* ws = (float*)d_ws;
  float* w_buf    = ws;                                  // B*T*M  = 1,638,400
  float* e_buf    = w_buf + (size_t)BB * TT * MM;        // B*T*64 = 2,097,152
  float* a_buf    = e_buf + (size_t)BB * TT * 64;        // B*T*64 = 2,097,152
  float* read_buf = a_buf + (size_t)BB * TT * 64;        // B*(T-1)*64 = 2,093,056

  hipLaunchKernelGGL(k1_pre, dim3(512), dim3(256), 0, stream,
                     question, response, k_emb, v_emb, Mk, e_W, e_b, a_W, a_b,
                     w_buf, e_buf, a_buf);
  hipLaunchKernelGGL(k2_scan, dim3(64), dim3(256), 0, stream,
                     w_buf, e_buf, a_buf, mask, Mv0, read_buf);
  hipLaunchKernelGGL(k3_out, dim3(512), dim3(256), 0, stream,
                     question, k_emb, read_buf, f_W, f_b, p_W, p_b, out);
}

// Round 2
// 221.510 us; speedup vs baseline: 2.1082x; 2.1082x over previous
//
#include <hip/hip_runtime.h>
#include <hip/hip_bf16.h>
#include <cstddef>

// Problem constants (from reference)
#define QN 10000
#define DD 64
#define MM 50
#define BB 64
#define TT 512
#define WPAD 52   // padded w row stride in floats (208 B -> 16B-aligned rows)

// ---------------------------------------------------------------------------
// k1a: w = softmax(k @ Mk^T). One wave per row; Mk row in VGPRs (64 regs).
// ---------------------------------------------------------------------------
__global__ __launch_bounds__(256) void k1a_w(
    const int* __restrict__ question, const float* __restrict__ k_emb,
    const float* __restrict__ Mk, float* __restrict__ w_buf) {
  const int lane = threadIdx.x & 63;
  const int wslot = __builtin_amdgcn_readfirstlane((int)(threadIdx.x >> 6));
  const int wid = blockIdx.x * 4 + wslot;

  float mk[64];
  const int mrow = lane < MM ? lane : (MM - 1);
#pragma unroll
  for (int i = 0; i < 64; i += 4) {
    const float4 t4 = *(const float4*)(Mk + mrow * 64 + i);
    mk[i] = t4.x; mk[i + 1] = t4.y; mk[i + 2] = t4.z; mk[i + 3] = t4.w;
  }

  for (int row = wid; row < BB * TT; row += 2048) {
    const int q = question[row];                       // wave-uniform
    const float* __restrict__ krow = k_emb + (size_t)q * 64;
    // 4-way split accumulators to break the fma dependency chain
    float l0 = 0.f, l1 = 0.f, l2 = 0.f, l3 = 0.f;
#pragma unroll
    for (int i = 0; i < 64; i += 4) {
      const float4 kv = *(const float4*)(krow + i);    // uniform -> s_load_dwordx4
      l0 = fmaf(kv.x, mk[i], l0);
      l1 = fmaf(kv.y, mk[i + 1], l1);
      l2 = fmaf(kv.z, mk[i + 2], l2);
      l3 = fmaf(kv.w, mk[i + 3], l3);
    }
    const float lm = (l0 + l1) + (l2 + l3);
    float lv = (lane < MM) ? lm : -3.4e38f;
#pragma unroll
    for (int off = 32; off > 0; off >>= 1) lv = fmaxf(lv, __shfl_xor(lv, off));
    float pe = (lane < MM) ? __expf(lm - lv) : 0.f;
    float ss = pe;
#pragma unroll
    for (int off = 32; off > 0; off >>= 1) ss += __shfl_xor(ss, off);
    if (lane < MM) w_buf[(size_t)row * WPAD + lane] = pe / ss;
  }
}

// ---------------------------------------------------------------------------
// k1b: e = sigmoid(v@e_W+e_b), a = tanh(v@a_W+a_b). One wave per row;
// e_W/a_W columns in VGPRs (128 regs).
// ---------------------------------------------------------------------------
__global__ __launch_bounds__(256) void k1b_ea(
    const int* __restrict__ question, const int* __restrict__ response,
    const float* __restrict__ v_emb,
    const float* __restrict__ e_W, const float* __restrict__ e_b,
    const float* __restrict__ a_W, const float* __restrict__ a_b,
    float* __restrict__ e_buf, float* __restrict__ a_buf) {
  const int lane = threadIdx.x & 63;
  const int wslot = __builtin_amdgcn_readfirstlane((int)(threadIdx.x >> 6));
  const int wid = blockIdx.x * 4 + wslot;

  float ew[64], aw[64];
#pragma unroll
  for (int i = 0; i < 64; ++i) {
    ew[i] = e_W[i * 64 + lane];
    aw[i] = a_W[i * 64 + lane];
  }
  const float eb = e_b[lane];
  const float ab = a_b[lane];

  for (int row = wid; row < BB * TT; row += 2048) {
    const int q = question[row];
    const int r = response[row];
    const float* __restrict__ vrow = v_emb + ((size_t)q + (size_t)QN * r) * 64;
    float e0 = eb, e1 = 0.f, a0 = ab, a1 = 0.f;
#pragma unroll
    for (int i = 0; i < 64; i += 2) {
      const float2 vv = *(const float2*)(vrow + i);    // uniform -> s_load
      e0 = fmaf(vv.x, ew[i], e0);
      a0 = fmaf(vv.x, aw[i], a0);
      e1 = fmaf(vv.y, ew[i + 1], e1);
      a1 = fmaf(vv.y, aw[i + 1], a1);
    }
    const float se = e0 + e1, sa = a0 + a1;
    const float ev = 1.f / (1.f + __expf(-se));
    const float t2 = __expf(2.f * sa);
    const float av = 1.f - 2.f / (t2 + 1.f);           // tanh
    e_buf[(size_t)row * 64 + lane] = ev;
    a_buf[(size_t)row * 64 + lane] = av;
  }
}

// ---------------------------------------------------------------------------
// kA: per-(b,chunk) composed affine transform per (m,d).
// One wave per unit (b*C+c); lane = d; all 50 m's in registers. No barriers.
//   s_out = A*s_in + B with per-step alpha = 1 - w*e, beta = w*a (identity if
//   mask != 1). Ascending t: A *= alpha; B = B*alpha + beta.
// ---------------------------------------------------------------------------
__global__ __launch_bounds__(256) void kA_chunk(
    const float* __restrict__ w_buf, const float* __restrict__ e_buf,
    const float* __restrict__ a_buf, const float* __restrict__ mask,
    float* __restrict__ A_arr, float* __restrict__ B_arr, int logC, int L) {
  const int lane = threadIdx.x & 63;
  const int wslot = __builtin_amdgcn_readfirstlane((int)(threadIdx.x >> 6));
  const int unit = blockIdx.x * 4 + wslot;             // = b*C + c
  const int C = 1 << logC;
  if (unit >= BB * C) return;
  const int b = unit >> logC;
  const int c = unit & (C - 1);

  float Am[MM], Bm[MM];
#pragma unroll
  for (int m = 0; m < MM; ++m) { Am[m] = 1.f; Bm[m] = 0.f; }

  const int t0 = c * L;
  for (int j = 0; j < L; ++j) {
    const size_t row = (size_t)b * TT + (t0 + j);
    const float ed = e_buf[row * 64 + lane];
    const float ad = a_buf[row * 64 + lane];
    const float mv = mask[row];                        // wave-uniform
    const float* __restrict__ wr = w_buf + row * WPAD; // uniform -> s_loads
    if (mv == 1.0f) {
#pragma unroll
      for (int m = 0; m < MM; ++m) {
        const float wm = wr[m];
        const float al = fmaf(-wm, ed, 1.0f);
        const float be = wm * ad;
        Am[m] *= al;
        Bm[m] = fmaf(Bm[m], al, be);
      }
    }
  }
  float* __restrict__ Ad = A_arr + (size_t)unit * (MM * 64);
  float* __restrict__ Bd = B_arr + (size_t)unit * (MM * 64);
#pragma unroll
  for (int m = 0; m < MM; ++m) {
    Ad[m * 64 + lane] = Am[m];
    Bd[m * 64 + lane] = Bm[m];
  }
}

// ---------------------------------------------------------------------------
// kB: sequential over C chunks, parallel over B*M*D = 204,800 elements.
// entry[c] = state before chunk c; s <- A[c]*s + B[c]. 1-deep prefetch.
// ---------------------------------------------------------------------------
__global__ __launch_bounds__(256) void kB_entry(
    const float* __restrict__ A_arr, const float* __restrict__ B_arr,
    const float* __restrict__ Mv0, float* __restrict__ entry, int C) {
  const int idx = blockIdx.x * 256 + (int)threadIdx.x; // < B*3200
  const int b = idx / (MM * 64);
  const int r = idx - b * (MM * 64);                   // m*64 + d
  float s = Mv0[r];
  const size_t base = (size_t)b * C * (MM * 64) + r;
  float Ac = A_arr[base];
  float Bc = B_arr[base];
  for (int c = 0; c < C; ++c) {
    entry[base + (size_t)c * (MM * 64)] = s;
    float An = 1.f, Bn = 0.f;
    if (c + 1 < C) {
      An = A_arr[base + (size_t)(c + 1) * (MM * 64)];
      Bn = B_arr[base + (size_t)(c + 1) * (MM * 64)];
    }
    s = fmaf(Ac, s, Bc);
    Ac = An; Bc = Bn;
  }
}

// ---------------------------------------------------------------------------
// kC: replay each chunk from its entry state, emitting reads.
// One wave per unit (b*C+c); lane = d; s[50] in registers; w in SGPRs.
// read at output index t-1 uses w_t and the pre-update state. No barriers.
// ---------------------------------------------------------------------------
__global__ __launch_bounds__(256) void kC_read(
    const float* __restrict__ w_buf, const float* __restrict__ e_buf,
    const float* __restrict__ a_buf, const float* __restrict__ mask,
    const float* __restrict__ entry, const float* __restrict__ Mv0,
    float* __restrict__ read_buf, int logC, int L, int use_mv0) {
  const int lane = threadIdx.x & 63;
  const int wslot = __builtin_amdgcn_readfirstlane((int)(threadIdx.x >> 6));
  const int unit = blockIdx.x * 4 + wslot;             // = b*C + c
  const int C = 1 << logC;
  if (unit >= BB * C) return;
  const int b = unit >> logC;
  const int c = unit & (C - 1);

  float s[MM];
  if (use_mv0) {
#pragma unroll
    for (int m = 0; m < MM; ++m) s[m] = Mv0[m * 64 + lane];
  } else {
    const float* __restrict__ ep = entry + (size_t)unit * (MM * 64);
#pragma unroll
    for (int m = 0; m < MM; ++m) s[m] = ep[m * 64 + lane];
  }

  const int t0 = c * L;
  for (int j = 0; j < L; ++j) {
    const int t = t0 + j;
    const size_t row = (size_t)b * TT + t;
    const float* __restrict__ wr = w_buf + row * WPAD; // uniform -> s_loads
    const float ed = e_buf[row * 64 + lane];
    const float ad = a_buf[row * 64 + lane];
    const float mv = mask[row];

    if (t >= 1) {
      float a0 = 0.f, a1 = 0.f;
#pragma unroll
      for (int m = 0; m < MM; m += 2) {
        a0 = fmaf(wr[m], s[m], a0);
        a1 = fmaf(wr[m + 1], s[m + 1], a1);
      }
      // MM = 50 is even, so the pairing above covers exactly m = 0..49
      read_buf[((size_t)b * (TT - 1) + (t - 1)) * 64 + lane] = a0 + a1;
    }
    if (mv == 1.0f) {
#pragma unroll
      for (int m = 0; m < MM; ++m)
        s[m] = fmaf(wr[m], fmaf(-s[m], ed, ad), s[m]);
    }
  }
}

// ---------------------------------------------------------------------------
// k3: f = tanh([read | k_{t+1}] @ f_W + f_b); p = f @ p_W + p_b
// ---------------------------------------------------------------------------
__global__ __launch_bounds__(256) void k3_out(
    const int* __restrict__ question, const float* __restrict__ k_emb,
    const float* __restrict__ read_buf,
    const float* __restrict__ f_W, const float* __restrict__ f_b,
    const float* __restrict__ p_W, const float* __restrict__ p_b,
    float* __restrict__ out) {
  const int lane = threadIdx.x & 63;
  const int wslot = __builtin_amdgcn_readfirstlane((int)(threadIdx.x >> 6));
  const int wid = blockIdx.x * 4 + wslot;

  float fw[128];
#pragma unroll
  for (int i = 0; i < 128; ++i) fw[i] = f_W[i * 64 + lane];
  const float fb = f_b[lane];
  const float pw = p_W[lane];
  const float pb = p_b[0];

  for (int row = wid; row < BB * (TT - 1); row += 2048) {
    const int b = row / (TT - 1);
    const int tp = row - b * (TT - 1);
    const float* __restrict__ rrow = read_buf + (size_t)row * 64;
    const int qn = question[b * TT + tp + 1];          // wave-uniform
    const float* __restrict__ krow = k_emb + (size_t)qn * 64;

    float f0 = fb, f1 = 0.f, f2 = 0.f, f3 = 0.f;
#pragma unroll
    for (int i = 0; i < 64; i += 4) {
      const float4 rv = *(const float4*)(rrow + i);
      f0 = fmaf(rv.x, fw[i], f0);
      f1 = fmaf(rv.y, fw[i + 1], f1);
      f2 = fmaf(rv.z, fw[i + 2], f2);
      f3 = fmaf(rv.w, fw[i + 3], f3);
    }
#pragma unroll
    for (int i = 0; i < 64; i += 4) {
      const float4 kv = *(const float4*)(krow + i);
      f0 = fmaf(kv.x, fw[64 + i], f0);
      f1 = fmaf(kv.y, fw[64 + i + 1], f1);
      f2 = fmaf(kv.z, fw[64 + i + 2], f2);
      f3 = fmaf(kv.w, fw[64 + i + 3], f3);
    }
    const float f = (f0 + f1) + (f2 + f3);
    const float t2 = __expf(2.f * f);
    const float fv = 1.f - 2.f / (t2 + 1.f);           // tanh

    float acc = fv * pw;
#pragma unroll
    for (int off = 32; off > 0; off >>= 1) acc += __shfl_xor(acc, off);
    if (lane == 0) out[row] = acc + pb;
  }
}

// ---------------------------------------------------------------------------
extern "C" void kernel_launch(void* const* d_in, const int* in_sizes, int n_in,
                              void* d_out, int out_size, void* d_ws, size_t ws_size,
                              hipStream_t stream) {
  const int*   question = (const int*)d_in[0];
  const int*   response = (const int*)d_in[1];
  const float* mask     = (const float*)d_in[2];
  const float* k_emb    = (const float*)d_in[3];
  const float* v_emb    = (const float*)d_in[4];
  const float* Mk       = (const float*)d_in[5];
  const float* Mv0      = (const float*)d_in[6];
  const float* e_W      = (const float*)d_in[7];
  const float* e_b      = (const float*)d_in[8];
  const float* a_W      = (const float*)d_in[9];
  const float* a_b      = (const float*)d_in[10];
  const float* f_W      = (const float*)d_in[11];
  const float* f_b      = (const float*)d_in[12];
  const float* p_W      = (const float*)d_in[13];
  const float* p_b      = (const float*)d_in[14];
  float* out = (float*)d_out;

  // workspace layout (floats)
  const size_t wN = (size_t)BB * TT * WPAD;      // 1,703,936
  const size_t eN = (size_t)BB * TT * 64;        // 2,097,152
  const size_t rN = (size_t)BB * (TT - 1) * 64;  // 2,093,056
  float* ws = (float*)d_ws;
  float* w_buf    = ws;
  float* e_buf    = w_buf + wN;
  float* a_buf    = e_buf + eN;
  float* read_buf = a_buf + eN;
  float* A_arr    = read_buf + rN;
  const size_t baseN = wN + 2 * eN + rN;         // 7,991,296 floats

  // choose the largest chunk count C that fits the workspace
  int C = 32, logC = 5;
  while (C >= 2) {
    const size_t need = (baseN + 3ull * BB * MM * 64 * C) * sizeof(float);
    if (need <= ws_size) break;
    C >>= 1; logC -= 1;
  }
  const int useChunks = (C >= 2);
  if (!useChunks) { C = 1; logC = 0; }
  const int L = TT / C;
  float* B_arr = A_arr + (size_t)BB * C * MM * 64;
  float* entry = B_arr + (size_t)BB * C * MM * 64;

  hipLaunchKernelGGL(k1a_w, dim3(512), dim3(256), 0, stream,
                     question, k_emb, Mk, w_buf);
  hipLaunchKernelGGL(k1b_ea, dim3(512), dim3(256), 0, stream,
                     question, response, v_emb, e_W, e_b, a_W, a_b, e_buf, a_buf);

  const int units = BB * C;
  const int ublocks = (units + 3) / 4;
  if (useChunks) {
    hipLaunchKernelGGL(kA_chunk, dim3(ublocks), dim3(256), 0, stream,
                       w_buf, e_buf, a_buf, mask, A_arr, B_arr, logC, L);
    hipLaunchKernelGGL(kB_entry, dim3((BB * MM * 64) / 256), dim3(256), 0, stream,
                       A_arr, B_arr, Mv0, entry, C);
  }
  hipLaunchKernelGGL(kC_read, dim3(ublocks), dim3(256), 0, stream,
                     w_buf, e_buf, a_buf, mask, entry, Mv0, read_buf,
                     logC, L, useChunks ? 0 : 1);

  hipLaunchKernelGGL(k3_out, dim3(512), dim3(256), 0, stream,
                     question, k_emb, read_buf, f_W, f_b, p_W, p_b, out);
}